// Round 11
// baseline (386.208 us; speedup 1.0000x reference)
//
#include <hip/hip_runtime.h>

// ---------------------------------------------------------------------------
// MultiHeadAttention fwd: out = softmax_causal((qWq^T+bq)(kWk^T+bk)^T/8)(vWv^T+bv) Wo^T + bo
// B=2 S=2048 D=1024 H=16 DK=64.  All GEMM-shaped compute in f16 MFMA, fp32 accum.
// ---------------------------------------------------------------------------

typedef _Float16 f16;
typedef __attribute__((ext_vector_type(4))) float   f32x4;
typedef __attribute__((ext_vector_type(8))) _Float16 f16x8;

#define DEVI __device__ __forceinline__

static constexpr int S  = 2048;
static constexpr int D  = 1024;
static constexpr int KK = 1024;           // GEMM inner dim
static constexpr int M  = 4096;           // B*S

DEVI void gload_lds16(const void* g, void* l) {
  __builtin_amdgcn_global_load_lds((const __attribute__((address_space(1))) void*)g,
                                   (__attribute__((address_space(3))) void*)l, 16, 0, 0);
}

DEVI f32x4 mfma16(f16x8 a, f16x8 b, f32x4 c) {
  return __builtin_amdgcn_mfma_f32_16x16x32_f16(a, b, c, 0, 0, 0);
}

// XOR swizzle for 128-byte LDS rows: spreads 16B chunks across banks.
DEVI int xorv(int row) { return ((row ^ (row >> 3)) & 7) << 4; }

// ---------------------------------------------------------------------------
// fp32 -> f16 conversion, 8 elems/thread. blockIdx.y selects source array.
// ---------------------------------------------------------------------------
__global__ __launch_bounds__(256) void cvt_kernel(const float* __restrict__ s0,
                                                  const float* __restrict__ s1,
                                                  const float* __restrict__ s2,
                                                  const float* __restrict__ s3,
                                                  f16* __restrict__ dst, int nper) {
  const float* s = blockIdx.y == 0 ? s0 : blockIdx.y == 1 ? s1 : blockIdx.y == 2 ? s2 : s3;
  f16* d = dst + (size_t)blockIdx.y * nper;
  const int i = (blockIdx.x * 256 + threadIdx.x) * 8;
  f32x4 a = *(const f32x4*)(s + i);
  f32x4 b = *(const f32x4*)(s + i + 4);
  f16x8 r;
#pragma unroll
  for (int j = 0; j < 4; ++j) { r[j] = (f16)a[j]; r[4 + j] = (f16)b[j]; }
  *(f16x8*)(d + i) = r;
}

// ---------------------------------------------------------------------------
// GEMM mainloop (m97 structure): C[128,128] tile, A[M,K] row-major,
// W[N,K] row-major (i.e. x @ W^T), BK=32, 4 waves each 64x64.
// ---------------------------------------------------------------------------
DEVI void gemm_mainloop(const f16* __restrict__ A, const f16* __restrict__ W,
                        int m0, int n0, f16* As, f16* Bs, f32x4 acc[4][4]) {
  const int tid  = threadIdx.x;
  const int wid  = tid >> 6;
  const int lane = tid & 63;
  const int wr = wid >> 1, wc = wid & 1;

  const f32x4 z4 = {0.f, 0.f, 0.f, 0.f};
#pragma unroll
  for (int mi = 0; mi < 4; ++mi)
#pragma unroll
    for (int ni = 0; ni < 4; ++ni) acc[mi][ni] = z4;

  // staging geometry: 512 slots of 16B per 8KB tile; slot -> row=slot>>2, col=(slot&3)*8
  const int r0 = tid >> 2, c0 = (tid & 3) * 8;
  const int r1 = 64 + r0;
  const f16* Ag0 = A + (size_t)(m0 + r0) * KK + c0;
  const f16* Ag1 = A + (size_t)(m0 + r1) * KK + c0;
  const f16* Bg0 = W + (size_t)(n0 + r0) * KK + c0;
  const f16* Bg1 = W + (size_t)(n0 + r1) * KK + c0;
  f16* As0 = As + wid * 512;        // wave-uniform LDS dest (lane*16B implicit)
  f16* As1 = As + 2048 + wid * 512;
  f16* Bs0 = Bs + wid * 512;
  f16* Bs1 = Bs + 2048 + wid * 512;

  const int arow = wr * 64 + (lane & 15);
  const int brow = wc * 64 + (lane & 15);
  const int ko   = (lane >> 4) * 8;

  for (int k0 = 0; k0 < KK; k0 += 32) {
    gload_lds16(Ag0 + k0, As0);
    gload_lds16(Ag1 + k0, As1);
    gload_lds16(Bg0 + k0, Bs0);
    gload_lds16(Bg1 + k0, Bs1);
    __syncthreads();
    f16x8 af[4], bf[4];
#pragma unroll
    for (int mi = 0; mi < 4; ++mi) af[mi] = *(const f16x8*)&As[(arow + mi * 16) * 32 + ko];
#pragma unroll
    for (int ni = 0; ni < 4; ++ni) bf[ni] = *(const f16x8*)&Bs[(brow + ni * 16) * 32 + ko];
#pragma unroll
    for (int mi = 0; mi < 4; ++mi)
#pragma unroll
      for (int ni = 0; ni < 4; ++ni)
        acc[mi][ni] = mfma16(af[mi], bf[ni], acc[mi][ni]);
    __syncthreads();
  }
}

// QKV projection: z selects (X, W, bias, dst). Writes head layout [bh][s][64].
// z==0 (Q) additionally multiplies by 1/sqrt(DK)=0.125.
__global__ __launch_bounds__(256, 2) void gemm_qkv_kernel(const f16* __restrict__ X,
                                                          const f16* __restrict__ Wp,
                                                          const float* __restrict__ b0,
                                                          const float* __restrict__ b1,
                                                          const float* __restrict__ b2,
                                                          f16* __restrict__ Hd) {
  __shared__ f16 As[128 * 32];
  __shared__ f16 Bs[128 * 32];
  const int z = blockIdx.z;
  const f16* A = X + (size_t)z * (M * KK);
  const f16* W = Wp + (size_t)z * (D * KK);
  const float* bias = z == 0 ? b0 : z == 1 ? b1 : b2;
  f16* dst = Hd + (size_t)z * (size_t)4194304;
  const float scale = (z == 0) ? 0.125f : 1.0f;
  const int m0 = blockIdx.y * 128, n0 = blockIdx.x * 128;

  f32x4 acc[4][4];
  gemm_mainloop(A, W, m0, n0, As, Bs, acc);

  const int lane = threadIdx.x & 63, wid = threadIdx.x >> 6;
  const int wr = wid >> 1, wc = wid & 1;
#pragma unroll
  for (int ni = 0; ni < 4; ++ni) {
    const int col = n0 + wc * 64 + ni * 16 + (lane & 15);
    const float bv = bias[col];
    const int h = col >> 6, dk = col & 63;
#pragma unroll
    for (int mi = 0; mi < 4; ++mi) {
#pragma unroll
      for (int r = 0; r < 4; ++r) {
        const int row = m0 + wr * 64 + mi * 16 + (lane >> 4) * 4 + r;
        const int bb = row >> 11, ss = row & 2047;
        dst[(size_t)((bb * 16 + h) * 2048 + ss) * 64 + dk] = (f16)((acc[mi][ni][r] + bv) * scale);
      }
    }
  }
}

// Output projection: plain [M,1024] fp32 output.
__global__ __launch_bounds__(256, 2) void gemm_out_kernel(const f16* __restrict__ A,
                                                          const f16* __restrict__ W,
                                                          const float* __restrict__ bias,
                                                          float* __restrict__ out) {
  __shared__ f16 As[128 * 32];
  __shared__ f16 Bs[128 * 32];
  const int m0 = blockIdx.y * 128, n0 = blockIdx.x * 128;
  f32x4 acc[4][4];
  gemm_mainloop(A, W, m0, n0, As, Bs, acc);
  const int lane = threadIdx.x & 63, wid = threadIdx.x >> 6;
  const int wr = wid >> 1, wc = wid & 1;
#pragma unroll
  for (int ni = 0; ni < 4; ++ni) {
    const int col = n0 + wc * 64 + ni * 16 + (lane & 15);
    const float bv = bias[col];
#pragma unroll
    for (int mi = 0; mi < 4; ++mi) {
#pragma unroll
      for (int r = 0; r < 4; ++r) {
        const int row = m0 + wr * 64 + mi * 16 + (lane >> 4) * 4 + r;
        out[(size_t)row * 1024 + col] = acc[mi][ni][r] + bv;
      }
    }
  }
}

// ---------------------------------------------------------------------------
// V transpose: Vh[bh][s][64] -> VhT[bh][64][s].  LDS-tiled, coalesced both ways.
// ---------------------------------------------------------------------------
__global__ __launch_bounds__(256) void vtr_kernel(const f16* __restrict__ Vh,
                                                  f16* __restrict__ VhT) {
  __shared__ f16 T[64][72];               // +8 pad: column reads conflict-light
  const int bh = blockIdx.y;
  const int s0 = blockIdx.x * 64;
  const size_t base = (size_t)bh * (S * 64);
  const int tid = threadIdx.x;
#pragma unroll
  for (int i = 0; i < 2; ++i) {
    const int c = i * 256 + tid;
    const int sr = c >> 3, sc = (c & 7) * 8;
    f16x8 v = *(const f16x8*)&Vh[base + (size_t)(s0 + sr) * 64 + sc];
    *(f16x8*)&T[sr][sc] = v;              // row stride 144B, 16B-aligned
  }
  __syncthreads();
#pragma unroll
  for (int i = 0; i < 2; ++i) {
    const int c = i * 256 + tid;
    const int dk = c >> 3, so = (c & 7) * 8;
    f16x8 r;
#pragma unroll
    for (int j = 0; j < 8; ++j) r[j] = T[so + j][dk];
    *(f16x8*)&VhT[base + (size_t)dk * S + s0 + so] = r;
  }
}

// ---------------------------------------------------------------------------
// Flash attention, causal, SPLIT-KV x2 (flash-decoding).  Block = (128 q-rows,
// one bh, one kv-half).  4 waves x 32 rows.  KVBLK=64, K/V double-buffered with
// counted vmcnt across raw barriers.  Writes UNNORMALIZED partial O~ (f16) and
// per-row (m,l) f32; comb_kernel merges the two halves.
// ntiles = q0/64+2 is always even, so halves are equal (t in [z*h, z*h+h)).
// blockIdx.x reversed so longest blocks dispatch first.
// ---------------------------------------------------------------------------
__global__ __launch_bounds__(256, 3) void attn_kernel(const f16* __restrict__ Qh,
                                                      const f16* __restrict__ Kh,
                                                      const f16* __restrict__ VhT,
                                                      f16* __restrict__ pO,
                                                      float2* __restrict__ ml) {
  __shared__ f16 Ks[2][64 * 64];   // rows = kv, 128B rows, XOR-swizzled content
  __shared__ f16 Vt[2][64 * 64];   // rows = dk, cols = kv, XOR-swizzled content
  __shared__ f16 Ps[4][32 * 64];   // per-wave P tile, rows = q-local, swizzled

  const int tid = threadIdx.x, wid = tid >> 6, lane = tid & 63;
  const int bh = blockIdx.y;
  const int z  = blockIdx.z;
  const int q0 = (15 - (int)blockIdx.x) * 128;
  const int qw = q0 + wid * 32;                 // this wave's q base (seq index)
  const size_t base = (size_t)bh * (S * 64);

  // kv-half bounds: ntiles = q0/64 + 2 (even); this block does [t0, t1)
  const int half = q0 / 128 + 1;
  const int t0 = z * half, t1 = t0 + half;

  // staging slot geometry (256 threads, 2 slots each per K and V)
  const int srow0 = tid >> 3;                    // slot 0 row
  const int scol0 = (((tid & 7) * 16) ^ xorv(srow0)) >> 1;
  const int srow1 = (256 + tid) >> 3;            // slot 1 row
  const int scol1 = (((tid & 7) * 16) ^ xorv(srow1)) >> 1;
  const int ldsoff0 = wid * 64 * 16;             // + lane*16 implicit
  const int ldsoff1 = (256 + wid * 64) * 16;

  // Q fragments: aq[mi][ks] ; A-operand layout row=lane&15, k=(lane>>4)*8
  f16x8 aq[2][2];
#pragma unroll
  for (int mi = 0; mi < 2; ++mi)
#pragma unroll
    for (int ks = 0; ks < 2; ++ks)
      aq[mi][ks] = *(const f16x8*)&Qh[base + (size_t)(qw + mi * 16 + (lane & 15)) * 64 +
                                      ks * 32 + (lane >> 4) * 8];

  const f32x4 z4 = {0.f, 0.f, 0.f, 0.f};
  f32x4 o[2][4];
  float mrow[2][4], lrow[2][4];
#pragma unroll
  for (int mi = 0; mi < 2; ++mi)
#pragma unroll
    for (int r = 0; r < 4; ++r) { mrow[mi][r] = -1e30f; lrow[mi][r] = 0.f; }
#pragma unroll
  for (int mi = 0; mi < 2; ++mi)
#pragma unroll
    for (int dj = 0; dj < 4; ++dj) o[mi][dj] = z4;

  // prologue: stage tile t0 into buffer 0
  {
    const int kv0 = t0 * 64;
    gload_lds16(Kh + base + (size_t)(kv0 + srow0) * 64 + scol0, (char*)Ks[0] + ldsoff0);
    gload_lds16(VhT + base + (size_t)srow0 * S + kv0 + scol0,   (char*)Vt[0] + ldsoff0);
    gload_lds16(Kh + base + (size_t)(kv0 + srow1) * 64 + scol1, (char*)Ks[0] + ldsoff1);
    gload_lds16(VhT + base + (size_t)srow1 * S + kv0 + scol1,   (char*)Vt[0] + ldsoff1);
  }

  int cur = 0;
  for (int t = t0; t < t1; ++t) {
    const int kv0 = t * 64;
    // ---- prefetch tile t+1 into the other buffer, then wait ONLY tile t ----
    if (t + 1 < t1) {
      const int kn = kv0 + 64;
      f16* Kd = Ks[cur ^ 1];
      f16* Vd = Vt[cur ^ 1];
      gload_lds16(Kh + base + (size_t)(kn + srow0) * 64 + scol0, (char*)Kd + ldsoff0);
      gload_lds16(VhT + base + (size_t)srow0 * S + kn + scol0,   (char*)Vd + ldsoff0);
      gload_lds16(Kh + base + (size_t)(kn + srow1) * 64 + scol1, (char*)Kd + ldsoff1);
      gload_lds16(VhT + base + (size_t)srow1 * S + kn + scol1,   (char*)Vd + ldsoff1);
      asm volatile("s_waitcnt vmcnt(4)" ::: "memory");
    } else {
      asm volatile("s_waitcnt vmcnt(0)" ::: "memory");
    }
    __builtin_amdgcn_sched_barrier(0);
    __builtin_amdgcn_s_barrier();
    __builtin_amdgcn_sched_barrier(0);

    const f16* Kc = Ks[cur];
    const f16* Vc = Vt[cur];

    if (kv0 <= qw + 31) {                       // wave has visible keys in this tile
      // ---- QK^T ----
      f32x4 sc[2][4];
#pragma unroll
      for (int mi = 0; mi < 2; ++mi)
#pragma unroll
        for (int nj = 0; nj < 4; ++nj) sc[mi][nj] = z4;
      __builtin_amdgcn_s_setprio(1);
#pragma unroll
      for (int nj = 0; nj < 4; ++nj) {
        const int krow = nj * 16 + (lane & 15);
#pragma unroll
        for (int ks = 0; ks < 2; ++ks) {
          f16x8 bk = *(const f16x8*)((const char*)Kc + krow * 128 +
                                     ((ks * 64 + (lane >> 4) * 16) ^ xorv(krow)));
          sc[0][nj] = mfma16(aq[0][ks], bk, sc[0][nj]);
          sc[1][nj] = mfma16(aq[1][ks], bk, sc[1][nj]);
        }
      }
      __builtin_amdgcn_s_setprio(0);
      // ---- causal mask ----
      if (kv0 + 63 > qw) {
#pragma unroll
        for (int mi = 0; mi < 2; ++mi)
#pragma unroll
          for (int nj = 0; nj < 4; ++nj)
#pragma unroll
            for (int r = 0; r < 4; ++r) {
              const int qq = qw + mi * 16 + (lane >> 4) * 4 + r;
              const int kv = kv0 + nj * 16 + (lane & 15);
              if (kv > qq) sc[mi][nj][r] = -1e30f;
            }
      }
      // ---- online softmax ----
      float mnew[2][4], scl[2][4], psum[2][4];
#pragma unroll
      for (int mi = 0; mi < 2; ++mi)
#pragma unroll
        for (int r = 0; r < 4; ++r) {
          float mx = fmaxf(fmaxf(sc[mi][0][r], sc[mi][1][r]), fmaxf(sc[mi][2][r], sc[mi][3][r]));
#pragma unroll
          for (int off = 1; off < 16; off <<= 1) mx = fmaxf(mx, __shfl_xor(mx, off));
          const float mn = fmaxf(mrow[mi][r], mx);
          mnew[mi][r] = mn;
          scl[mi][r]  = exp2f((mrow[mi][r] - mn) * 1.44269504f);
          psum[mi][r] = 0.f;
        }
#pragma unroll
      for (int mi = 0; mi < 2; ++mi)
#pragma unroll
      for (int nj = 0; nj < 4; ++nj) {
#pragma unroll
          for (int r = 0; r < 4; ++r) {
            const float p = exp2f((sc[mi][nj][r] - mnew[mi][r]) * 1.44269504f);
            psum[mi][r] += p;
            const int ql = mi * 16 + (lane >> 4) * 4 + r;
            const int kvl = nj * 16 + (lane & 15);
            *(f16*)((char*)Ps[wid] + ql * 128 + ((kvl * 2) ^ xorv(ql))) = (f16)p;
          }
        }
#pragma unroll
      for (int mi = 0; mi < 2; ++mi)
#pragma unroll
        for (int r = 0; r < 4; ++r) {
          float ps = psum[mi][r];
#pragma unroll
          for (int off = 1; off < 16; off <<= 1) ps += __shfl_xor(ps, off);
          lrow[mi][r] = lrow[mi][r] * scl[mi][r] + ps;
          mrow[mi][r] = mnew[mi][r];
        }
      // ---- rescale O ----
#pragma unroll
      for (int mi = 0; mi < 2; ++mi)
#pragma unroll
        for (int dj = 0; dj < 4; ++dj)
#pragma unroll
          for (int r = 0; r < 4; ++r) o[mi][dj][r] *= scl[mi][r];
      // ---- PV ----  (Ps writes above are same-wave; DS ops are in-order)
      __builtin_amdgcn_s_setprio(1);
#pragma unroll
      for (int ks = 0; ks < 2; ++ks) {
        f16x8 pa[2];
#pragma unroll
        for (int mi = 0; mi < 2; ++mi) {
          const int ql = mi * 16 + (lane & 15);
          pa[mi] = *(const f16x8*)((char*)Ps[wid] + ql * 128 +
                                   ((ks * 64 + (lane >> 4) * 16) ^ xorv(ql)));
        }
#pragma unroll
        for (int dj = 0; dj < 4; ++dj) {
          const int dr = dj * 16 + (lane & 15);
          f16x8 bv = *(const f16x8*)((const char*)Vc + dr * 128 +
                                     ((ks * 64 + (lane >> 4) * 16) ^ xorv(dr)));
          o[0][dj] = mfma16(pa[0], bv, o[0][dj]);
          o[1][dj] = mfma16(pa[1], bv, o[1][dj]);
        }
      }
      __builtin_amdgcn_s_setprio(0);
    }

    // all waves finished reading buf cur before next iteration's stage overwrites it
    __builtin_amdgcn_sched_barrier(0);
    __builtin_amdgcn_s_barrier();
    cur ^= 1;
  }

  // epilogue: write partial O~ (unnormalized, f16) + per-row (m,l) f32
  f16* po = pO + (size_t)z * 4194304 + (size_t)bh * 2048 * 64;
#pragma unroll
  for (int mi = 0; mi < 2; ++mi)
#pragma unroll
    for (int r = 0; r < 4; ++r) {
      const int qq = qw + mi * 16 + (lane >> 4) * 4 + r;
#pragma unroll
      for (int dj = 0; dj < 4; ++dj) {
        const int dk = dj * 16 + (lane & 15);
        po[(size_t)qq * 64 + dk] = (f16)o[mi][dj][r];
      }
      if ((lane & 15) == 0) {
        float2 v; v.x = mrow[mi][r]; v.y = lrow[mi][r];
        ml[(size_t)z * 65536 + bh * 2048 + qq] = v;
      }
    }
}

// ---------------------------------------------------------------------------
// Combine the two kv-half partials: O = (O0 e^{m0-m} + O1 e^{m1-m}) / (l0 e^{m0-m} + l1 e^{m1-m})
// One thread = one (row, 16-dk chunk).  262144 threads.
// ---------------------------------------------------------------------------
__global__ __launch_bounds__(256) void comb_kernel(const f16* __restrict__ pO,
                                                   const float2* __restrict__ ml,
                                                   f16* __restrict__ Ao) {
  const int gid = blockIdx.x * 256 + threadIdx.x;
  const int rid = gid >> 2;                     // 65536 rows (bh*2048+s)
  const int c0  = (gid & 3) * 16;
  const float2 a = ml[rid];
  const float2 b = ml[65536 + rid];
  const float m  = fmaxf(a.x, b.x);
  const float e0 = exp2f((a.x - m) * 1.44269504f);
  const float e1 = exp2f((b.x - m) * 1.44269504f);
  const float inv = 1.0f / (a.y * e0 + b.y * e1);
  const float s0 = e0 * inv, s1 = e1 * inv;
  const f16* p0 = pO + (size_t)rid * 64 + c0;
  const f16* p1 = p0 + 4194304;
  f16x8 x0 = *(const f16x8*)p0, x1 = *(const f16x8*)(p0 + 8);
  f16x8 y0 = *(const f16x8*)p1, y1 = *(const f16x8*)(p1 + 8);
  f16x8 r0, r1;
#pragma unroll
  for (int j = 0; j < 8; ++j) {
    r0[j] = (f16)((float)x0[j] * s0 + (float)y0[j] * s1);
    r1[j] = (f16)((float)x1[j] * s0 + (float)y1[j] * s1);
  }
  const int bh = rid >> 11, ss = rid & 2047;
  const int bb = bh >> 4, hh = bh & 15;
  f16* dst = Ao + (size_t)(bb * 2048 + ss) * 1024 + hh * 64 + c0;
  *(f16x8*)dst = r0;
  *(f16x8*)(dst + 8) = r1;
}

// ---------------------------------------------------------------------------
extern "C" void kernel_launch(void* const* d_in, const int* in_sizes, int n_in,
                              void* d_out, int out_size, void* d_ws, size_t ws_size,
                              hipStream_t stream) {
  const float* q  = (const float*)d_in[0];
  const float* k  = (const float*)d_in[1];
  const float* v  = (const float*)d_in[2];
  // d_in[3] = causal mask (tril), implemented structurally
  const float* Wq = (const float*)d_in[4];  const float* bq = (const float*)d_in[5];
  const float* Wk = (const float*)d_in[6];  const float* bk = (const float*)d_in[7];
  const float* Wv = (const float*)d_in[8];  const float* bv = (const float*)d_in[9];
  const float* Wo = (const float*)d_in[10]; const float* bo = (const float*)d_in[11];
  float* out = (float*)d_out;

  char* ws = (char*)d_ws;
  f16* xb = (f16*)(ws);                       // q,k,v f16: [0,24M), dead after gemm_qkv
  f16* wb = (f16*)(ws + 25165824);            // Wq,Wk,Wv,Wo f16: [24M,32M)
  f16* hb = (f16*)(ws + 33554432);            // Qh[32,40M) Kh[40,48M) Vh[48,56M)
  f16* ao = (f16*)(ws + 58720256);            // attention out [4096][1024]: [56M,64M)
  f16* vt = (f16*)(ws);                       // VhT[bh][64][2048]: [0,8M)   (xb dead)
  f16* po = (f16*)(ws + 8388608);             // partial O~ [2][65536][64] f16: [8M,24M)
  float2* mlp = (float2*)(ws + 50331648);     // (m,l) [2][65536] f32x2: 1M at +48M (Vh dead after vtr)
  // total 64 MiB

  cvt_kernel<<<dim3(2048, 3), 256, 0, stream>>>(q, k, v, nullptr, xb, 4194304);
  cvt_kernel<<<dim3(512, 4), 256, 0, stream>>>(Wq, Wk, Wv, Wo, wb, 1048576);
  gemm_qkv_kernel<<<dim3(8, 32, 3), 256, 0, stream>>>(xb, wb, bq, bk, bv, hb);
  vtr_kernel<<<dim3(32, 32), 256, 0, stream>>>(hb + 8388608, vt);
  attn_kernel<<<dim3(16, 32, 2), 256, 0, stream>>>(hb, hb + 4194304, vt, po, mlp);
  comb_kernel<<<1024, 256, 0, stream>>>(po, mlp, ao);
  gemm_out_kernel<<<dim3(8, 32), 256, 0, stream>>>(ao, wb + 3 * 1048576, bo, out);
}